// Round 6
// baseline (252.333 us; speedup 1.0000x reference)
//
#include <hip/hip_runtime.h>
#include <hip/hip_cooperative_groups.h>
#include <stdint.h>

namespace cg = cooperative_groups;

// WaveletSparsityPrior: 3-level Haar, loss = sum_lvl w_lvl * mean min(|c|, t_lvl)
// ONE cooperative dispatch (grid (4,128) x 256, 2 blocks/CU -> capacity-safe):
//   phase 1: block (xb,b) processes 4 sub-strips of batch b; all loads
//     lane-contiguous float4; Haar in registers (L1/L2 in-lane, L3 shfl_xor);
//     512-bin LDS histogram of |L3 details| -> plain-store ghist[b*4+xb];
//     per-block loss partial -> partials[b*4+xb]. Speculative t=0.2 (clip
//     top; exact — absmax=0 through R1-R5).
//   grid.sync()  (device-scope acq/rel — makes plain stores visible)
//   phase 2: wave 0 of block (0,b): sum 4 sub-hists, median bin -> sigma
//     (err <= 2e-3 << 2e-2), t, loss; 2 fp32 atomicAdds into d_out.
// Fallback (if coop launch fails): R5's two-kernel path, separate ws region.
//
// ws layout (floats): [0,512) partials4; [512, 512+262144) ghist4 (u32);
//   fallback: [262656, 264704) partials16; [264704, +1048576) ghist16 (u32).

static constexpr int BATCH = 128;
static constexpr int W = 512;
static constexpr int NBIN = 512;      // bin width 1/256 over [0,2)

__device__ __forceinline__ float block_reduce_sum(float v, float* lds) {
    #pragma unroll
    for (int off = 32; off > 0; off >>= 1)
        v += __shfl_down(v, off, 64);
    const int lane = threadIdx.x & 63;
    const int wave = threadIdx.x >> 6;
    if (lane == 0) lds[wave] = v;
    __syncthreads();
    if (threadIdx.x == 0) {
        float s = 0.0f;
        for (int w = 0; w < 4; ++w) s += lds[w];
        lds[0] = s;
    }
    __syncthreads();
    const float r = lds[0];
    __syncthreads();
    return r;
}

__device__ __forceinline__ void haar_quad(float a, float b, float c, float d,
                                          float& cA, float& cH, float& cV, float& cD) {
    const float sab = a + b, scd = c + d, dab = a - b, dcd = c - d;
    cA = 0.5f * (sab + scd);
    cH = 0.5f * (sab - scd);
    cV = 0.5f * (dab + dcd);
    cD = 0.5f * (dab - dcd);
}

// Per-thread 8x8 version (only on the never-taken correction path).
__device__ __forceinline__ float wavelet_block_loss(
        const float* __restrict__ blk, float t1, float t2, float t3) {
    float cA1[4][4];
    float s1 = 0.0f, s2 = 0.0f, s3 = 0.0f;
    #pragma unroll
    for (int rr = 0; rr < 4; ++rr) {
        const float4 r0a = *(const float4*)(blk + (size_t)(2 * rr) * W);
        const float4 r0b = *(const float4*)(blk + (size_t)(2 * rr) * W + 4);
        const float4 r1a = *(const float4*)(blk + (size_t)(2 * rr + 1) * W);
        const float4 r1b = *(const float4*)(blk + (size_t)(2 * rr + 1) * W + 4);
        const float top[8] = {r0a.x, r0a.y, r0a.z, r0a.w, r0b.x, r0b.y, r0b.z, r0b.w};
        const float bot[8] = {r1a.x, r1a.y, r1a.z, r1a.w, r1b.x, r1b.y, r1b.z, r1b.w};
        #pragma unroll
        for (int cc = 0; cc < 4; ++cc) {
            float cA, cH, cV, cD;
            haar_quad(top[2*cc], top[2*cc+1], bot[2*cc], bot[2*cc+1], cA, cH, cV, cD);
            s1 += fminf(fabsf(cH), t1) + fminf(fabsf(cV), t1) + fminf(fabsf(cD), t1);
            cA1[rr][cc] = cA;
        }
    }
    float cA2[2][2];
    #pragma unroll
    for (int rr = 0; rr < 2; ++rr)
        #pragma unroll
        for (int cc = 0; cc < 2; ++cc) {
            float cA, cH, cV, cD;
            haar_quad(cA1[2*rr][2*cc], cA1[2*rr][2*cc+1],
                      cA1[2*rr+1][2*cc], cA1[2*rr+1][2*cc+1], cA, cH, cV, cD);
            s2 += fminf(fabsf(cH), t2) + fminf(fabsf(cV), t2) + fminf(fabsf(cD), t2);
            cA2[rr][cc] = cA;
        }
    {
        float cA, cH, cV, cD;
        haar_quad(cA2[0][0], cA2[0][1], cA2[1][0], cA2[1][1], cA, cH, cV, cD);
        s3 = fminf(fabsf(cH), t3) + fminf(fabsf(cV), t3) + fminf(fabsf(cD), t3);
    }
    const float w1 = 1.0f / (9.0f * 65536.0f);
    const float w2 = 1.0f / (6.0f * 16384.0f);
    const float w3 = 1.0f / (3.0f * 4096.0f);
    return s1 * w1 + s2 * w2 + s3 * w3;
}

// Phase-1 strip worker: wave processes strip R (8 rows x 512 cols) of batch b.
// Accumulates s1/s2/s3 and bins |L3 details| into the block-shared histogram.
__device__ __forceinline__ void strip_work(const float* __restrict__ base,
                                           int R, int lane,
                                           float t1, float t2, float t3,
                                           float& s1, float& s2, float& s3,
                                           uint32_t* h) {
    const float* strip = base + (size_t)(R * 8) * W;
    float cA1A[4][2], cA1B[4][2];
    #pragma unroll
    for (int rp = 0; rp < 4; ++rp) {
        const float* r0 = strip + (size_t)(2 * rp) * W;
        const float* r1 = strip + (size_t)(2 * rp + 1) * W;
        const float4 tA = *(const float4*)(r0 + 4 * lane);
        const float4 bA = *(const float4*)(r1 + 4 * lane);
        const float4 tB = *(const float4*)(r0 + 256 + 4 * lane);
        const float4 bB = *(const float4*)(r1 + 256 + 4 * lane);
        float cA, cH, cV, cD;
        haar_quad(tA.x, tA.y, bA.x, bA.y, cA, cH, cV, cD);
        s1 += fminf(fabsf(cH), t1) + fminf(fabsf(cV), t1) + fminf(fabsf(cD), t1);
        cA1A[rp][0] = cA;
        haar_quad(tA.z, tA.w, bA.z, bA.w, cA, cH, cV, cD);
        s1 += fminf(fabsf(cH), t1) + fminf(fabsf(cV), t1) + fminf(fabsf(cD), t1);
        cA1A[rp][1] = cA;
        haar_quad(tB.x, tB.y, bB.x, bB.y, cA, cH, cV, cD);
        s1 += fminf(fabsf(cH), t1) + fminf(fabsf(cV), t1) + fminf(fabsf(cD), t1);
        cA1B[rp][0] = cA;
        haar_quad(tB.z, tB.w, bB.z, bB.w, cA, cH, cV, cD);
        s1 += fminf(fabsf(cH), t1) + fminf(fabsf(cV), t1) + fminf(fabsf(cD), t1);
        cA1B[rp][1] = cA;
    }
    float cA2A[2], cA2B[2];
    #pragma unroll
    for (int j = 0; j < 2; ++j) {
        float cA, cH, cV, cD;
        haar_quad(cA1A[2*j][0], cA1A[2*j][1], cA1A[2*j+1][0], cA1A[2*j+1][1],
                  cA, cH, cV, cD);
        s2 += fminf(fabsf(cH), t2) + fminf(fabsf(cV), t2) + fminf(fabsf(cD), t2);
        cA2A[j] = cA;
        haar_quad(cA1B[2*j][0], cA1B[2*j][1], cA1B[2*j+1][0], cA1B[2*j+1][1],
                  cA, cH, cV, cD);
        s2 += fminf(fabsf(cH), t2) + fminf(fabsf(cV), t2) + fminf(fabsf(cD), t2);
        cA2B[j] = cA;
    }
    const float pA0 = __shfl_xor(cA2A[0], 1, 64);
    const float pA1 = __shfl_xor(cA2A[1], 1, 64);
    const float pB0 = __shfl_xor(cA2B[0], 1, 64);
    const float pB1 = __shfl_xor(cA2B[1], 1, 64);
    if ((lane & 1) == 0) {
        float cA, cH, cV, cD;
        haar_quad(cA2A[0], pA0, cA2A[1], pA1, cA, cH, cV, cD);
        float aH = fabsf(cH), aV = fabsf(cV), aD = fabsf(cD);
        s3 += fminf(aH, t3) + fminf(aV, t3) + fminf(aD, t3);
        atomicAdd(&h[min((int)(aH * 256.0f), NBIN - 1)], 1u);
        atomicAdd(&h[min((int)(aV * 256.0f), NBIN - 1)], 1u);
        atomicAdd(&h[min((int)(aD * 256.0f), NBIN - 1)], 1u);
        haar_quad(cA2B[0], pB0, cA2B[1], pB1, cA, cH, cV, cD);
        aH = fabsf(cH); aV = fabsf(cV); aD = fabsf(cD);
        s3 += fminf(aH, t3) + fminf(aV, t3) + fminf(aD, t3);
        atomicAdd(&h[min((int)(aH * 256.0f), NBIN - 1)], 1u);
        atomicAdd(&h[min((int)(aV * 256.0f), NBIN - 1)], 1u);
        atomicAdd(&h[min((int)(aD * 256.0f), NBIN - 1)], 1u);
    }
}

// ---------------- cooperative single-dispatch kernel ----------------
__global__ __launch_bounds__(256, 2) void wavelet_coop(
        const float* __restrict__ x, float* __restrict__ partials,
        uint32_t* __restrict__ ghist, float* __restrict__ out) {
    __shared__ uint32_t h[NBIN];
    __shared__ float lds[8];
    const int tid  = threadIdx.x;
    const int lane = tid & 63;
    const int wv   = tid >> 6;
    const int xb   = blockIdx.x;   // 0..3
    const int b    = blockIdx.y;   // 0..127

    h[tid] = 0u;
    h[tid + 256] = 0u;
    if (xb == 0 && b == 0 && tid < 2) out[tid] = 0.0f;
    __syncthreads();

    const float BASE = 40.0f / 400.0f;
    const float t3 = BASE * 2.0f, t2 = t3 * 0.5f, t1 = t3 * 0.25f;
    const float* base = x + (size_t)b * W * W;

    float s1 = 0.0f, s2 = 0.0f, s3 = 0.0f;
    #pragma unroll 1
    for (int k = 0; k < 4; ++k) {
        const int sub = xb * 4 + k;          // 0..15
        strip_work(base, sub * 4 + wv, lane, t1, t2, t3, s1, s2, s3, h);
    }

    const float w1 = 1.0f / (9.0f * 65536.0f);
    const float w2 = 1.0f / (6.0f * 16384.0f);
    const float w3 = 1.0f / (3.0f * 4096.0f);
    const float part = s1 * w1 + s2 * w2 + s3 * w3;

    const float tot = block_reduce_sum(part, lds);   // barriers fence h[]
    if (tid == 0) partials[b * 4 + xb] = tot;

    uint32_t* gh = ghist + ((size_t)b * 4 + xb) * NBIN;
    gh[tid] = h[tid];
    gh[tid + 256] = h[tid + 256];

    cg::this_grid().sync();   // device-scope acq/rel: stores now visible

    // ---- phase 2: wave 0 of block (0, b) handles batch b ----
    if (xb != 0 || tid >= 64) return;

    uint32_t c[8] = {0, 0, 0, 0, 0, 0, 0, 0};
    #pragma unroll
    for (int s = 0; s < 4; ++s) {
        const uint32_t* hb = ghist + ((size_t)b * 4 + s) * NBIN + lane * 8;
        const uint4 u0 = *(const uint4*)(hb);
        const uint4 u1 = *(const uint4*)(hb + 4);
        c[0] += u0.x; c[1] += u0.y; c[2] += u0.z; c[3] += u0.w;
        c[4] += u1.x; c[5] += u1.y; c[6] += u1.z; c[7] += u1.w;
    }
    uint32_t lane_sum = 0;
    #pragma unroll
    for (int j = 0; j < 8; ++j) lane_sum += c[j];
    uint32_t incl = lane_sum;
    #pragma unroll
    for (int off = 1; off < 64; off <<= 1) {
        const uint32_t v = __shfl_up(incl, off, 64);
        if (lane >= off) incl += v;
    }
    uint32_t run = incl - lane_sum;
    int bin1 = 0x7FFFFFFF, bin2 = 0x7FFFFFFF;
    #pragma unroll
    for (int j = 0; j < 8; ++j) {
        const uint32_t nxt = run + c[j];
        if (run < 6144u && nxt >= 6144u) bin1 = lane * 8 + j;
        if (run < 6145u && nxt >= 6145u) bin2 = lane * 8 + j;
        run = nxt;
    }
    #pragma unroll
    for (int off = 32; off > 0; off >>= 1) {
        bin1 = min(bin1, __shfl_down(bin1, off, 64));
        bin2 = min(bin2, __shfl_down(bin2, off, 64));
    }
    bin1 = __shfl(bin1, 0, 64);
    bin2 = __shfl(bin2, 0, 64);

    const float v1 = ((float)bin1 + 0.5f) * (1.0f / 256.0f);
    const float v2 = ((float)bin2 + 0.5f) * (1.0f / 256.0f);
    const float med = 0.5f * (v1 + v2);
    const float sig = med * (float)(1.0 / 0.6745);
    const float TTOP = BASE * 2.0f;
    const float t = fminf(fmaxf(sig * 2.5f, BASE * 0.5f), TTOP);

    float loss_b;
    if (t == TTOP) {
        float v = (lane < 4) ? partials[b * 4 + lane] : 0.0f;
        #pragma unroll
        for (int off = 32; off > 0; off >>= 1) v += __shfl_down(v, off, 64);
        loss_b = v;
    } else {
        float part2 = 0.0f;
        #pragma unroll 1
        for (int k = 0; k < 64; ++k) {
            const int p = k * 64 + lane;
            const int i3 = p >> 6, j3 = p & 63;
            const float* blk = base + (size_t)(i3 * 8) * W + j3 * 8;
            part2 += wavelet_block_loss(blk, t * 0.25f, t * 0.5f, t);
        }
        #pragma unroll
        for (int off = 32; off > 0; off >>= 1) part2 += __shfl_down(part2, off, 64);
        loss_b = part2;
    }
    if (lane == 0) {
        atomicAdd(&out[0], loss_b * (1.0f / (float)BATCH));
        atomicAdd(&out[1], sig * (1.0f / (float)BATCH));
    }
}

// ---------------- fallback: R5's proven two-kernel path ----------------
__global__ __launch_bounds__(256) void pass_a(const float* __restrict__ x,
                                              float* __restrict__ partials,
                                              uint32_t* __restrict__ ghist,
                                              float* __restrict__ out) {
    __shared__ uint32_t h[NBIN];
    __shared__ float lds[8];
    const int tid = threadIdx.x, lane = tid & 63, wv = tid >> 6;
    const int sub = blockIdx.x, b = blockIdx.y;
    h[tid] = 0u; h[tid + 256] = 0u;
    if (sub == 0 && b == 0 && tid < 2) out[tid] = 0.0f;
    __syncthreads();
    const float BASE = 40.0f / 400.0f;
    const float t3 = BASE * 2.0f, t2 = t3 * 0.5f, t1 = t3 * 0.25f;
    float s1 = 0.0f, s2 = 0.0f, s3 = 0.0f;
    strip_work(x + (size_t)b * W * W, sub * 4 + wv, lane, t1, t2, t3, s1, s2, s3, h);
    const float w1 = 1.0f / (9.0f * 65536.0f);
    const float w2 = 1.0f / (6.0f * 16384.0f);
    const float w3 = 1.0f / (3.0f * 4096.0f);
    const float tot = block_reduce_sum(s1 * w1 + s2 * w2 + s3 * w3, lds);
    if (tid == 0) partials[b * 16 + sub] = tot;
    uint32_t* gh = ghist + ((size_t)b * 16 + sub) * NBIN;
    gh[tid] = h[tid];
    gh[tid + 256] = h[tid + 256];
}

__global__ __launch_bounds__(64) void pass_b(const uint32_t* __restrict__ ghist,
                                             const float* __restrict__ partials,
                                             const float* __restrict__ x,
                                             float* __restrict__ out) {
    const int b = blockIdx.x;
    const int lane = threadIdx.x;
    uint32_t c[8] = {0, 0, 0, 0, 0, 0, 0, 0};
    #pragma unroll 4
    for (int s = 0; s < 16; ++s) {
        const uint32_t* hb = ghist + ((size_t)b * 16 + s) * NBIN + lane * 8;
        const uint4 u0 = *(const uint4*)(hb);
        const uint4 u1 = *(const uint4*)(hb + 4);
        c[0] += u0.x; c[1] += u0.y; c[2] += u0.z; c[3] += u0.w;
        c[4] += u1.x; c[5] += u1.y; c[6] += u1.z; c[7] += u1.w;
    }
    uint32_t lane_sum = 0;
    #pragma unroll
    for (int j = 0; j < 8; ++j) lane_sum += c[j];
    uint32_t incl = lane_sum;
    #pragma unroll
    for (int off = 1; off < 64; off <<= 1) {
        const uint32_t v = __shfl_up(incl, off, 64);
        if (lane >= off) incl += v;
    }
    uint32_t run = incl - lane_sum;
    int bin1 = 0x7FFFFFFF, bin2 = 0x7FFFFFFF;
    #pragma unroll
    for (int j = 0; j < 8; ++j) {
        const uint32_t nxt = run + c[j];
        if (run < 6144u && nxt >= 6144u) bin1 = lane * 8 + j;
        if (run < 6145u && nxt >= 6145u) bin2 = lane * 8 + j;
        run = nxt;
    }
    #pragma unroll
    for (int off = 32; off > 0; off >>= 1) {
        bin1 = min(bin1, __shfl_down(bin1, off, 64));
        bin2 = min(bin2, __shfl_down(bin2, off, 64));
    }
    bin1 = __shfl(bin1, 0, 64);
    bin2 = __shfl(bin2, 0, 64);
    const float v1 = ((float)bin1 + 0.5f) * (1.0f / 256.0f);
    const float v2 = ((float)bin2 + 0.5f) * (1.0f / 256.0f);
    const float med = 0.5f * (v1 + v2);
    const float sig = med * (float)(1.0 / 0.6745);
    const float BASE = 40.0f / 400.0f;
    const float TTOP = BASE * 2.0f;
    const float t = fminf(fmaxf(sig * 2.5f, BASE * 0.5f), TTOP);
    float loss_b;
    if (t == TTOP) {
        float v = (lane < 16) ? partials[b * 16 + lane] : 0.0f;
        #pragma unroll
        for (int off = 32; off > 0; off >>= 1) v += __shfl_down(v, off, 64);
        loss_b = v;
    } else {
        float part = 0.0f;
        #pragma unroll 1
        for (int k = 0; k < 64; ++k) {
            const int p = k * 64 + lane;
            const int i3 = p >> 6, j3 = p & 63;
            const float* blk = x + (size_t)b * W * W + (size_t)(i3 * 8) * W + j3 * 8;
            part += wavelet_block_loss(blk, t * 0.25f, t * 0.5f, t);
        }
        #pragma unroll
        for (int off = 32; off > 0; off >>= 1) part += __shfl_down(part, off, 64);
        loss_b = part;
    }
    if (lane == 0) {
        atomicAdd(&out[0], loss_b * (1.0f / (float)BATCH));
        atomicAdd(&out[1], sig * (1.0f / (float)BATCH));
    }
}

extern "C" void kernel_launch(void* const* d_in, const int* in_sizes, int n_in,
                              void* d_out, int out_size, void* d_ws, size_t ws_size,
                              hipStream_t stream) {
    const float* x = (const float*)d_in[0];
    float* out = (float*)d_out;
    float* ws = (float*)d_ws;

    float*    partials4 = ws;                              // 512 f32
    uint32_t* ghist4    = (uint32_t*)(ws + 512);           // 128*4*512 = 1 MB
    float*    partials16= ws + 262656;                     // 2048 f32 (fallback)
    uint32_t* ghist16   = (uint32_t*)(ws + 264704);        // 128*16*512 (fallback)

    void* args[] = {(void*)&x, (void*)&partials4, (void*)&ghist4, (void*)&out};
    const hipError_t e = hipLaunchCooperativeKernel(
        (const void*)wavelet_coop, dim3(4, BATCH), dim3(256), args, 0, stream);
    if (e != hipSuccess) {
        dim3 grid(16, BATCH);
        pass_a<<<grid, 256, 0, stream>>>(x, partials16, ghist16, out);
        pass_b<<<BATCH, 64, 0, stream>>>(ghist16, partials16, x, out);
    }
}

// Round 7
// 242.356 us; speedup vs baseline: 1.0412x; 1.0412x over previous
//
#include <hip/hip_runtime.h>
#include <stdint.h>

// WaveletSparsityPrior: 3-level Haar, loss = sum_lvl w_lvl * mean min(|c|, t_lvl)
// Two dispatches: pass_a -> pass_b (R5 structure; R6's coop single-dispatch
// regressed: grid capped at 8 waves/CU -> latency-bound at 103 us).
//
//  pass_a (grid 16x128, 256 thr, __launch_bounds__(256,8) -> <=64 VGPR,
//    8 waves/SIMD = 100% occupancy — R6 counters showed the kernel is
//    latency-bound, VALUBusy 5%, so occupancy is the lever):
//    each WAVE owns an 8-row x 512-col strip, processed as two sequential
//    256-col halves to halve live registers. All loads lane-contiguous
//    float4. Haar L1/L2 in-lane, L3 via shfl_xor(1). 512-bin LDS histogram
//    of |L3 details| plain-stored to ghist[b][sub] (no memset needed).
//    Speculative t=0.2 (clip top) -> exact loss (absmax=0 through R1-R6).
//  pass_b (128 blocks x 64): sum 16 sub-hists, median bin -> sigma
//    (bin-midpoint err <= 2e-3 << 2e-2 threshold) -> t -> finalize via
//    2 fp32 atomicAdds. Correction recompute only if t != 0.2 (never taken).
//
// ws layout: f32 [0,2048) partials[b*16+sub]; u32 [2048, +128*16*512) ghist.

static constexpr int BATCH = 128;
static constexpr int W = 512;
static constexpr int NBIN = 512;      // bin width 1/256 over [0,2)

__device__ __forceinline__ float block_reduce_sum(float v, float* lds) {
    #pragma unroll
    for (int off = 32; off > 0; off >>= 1)
        v += __shfl_down(v, off, 64);
    const int lane = threadIdx.x & 63;
    const int wave = threadIdx.x >> 6;
    if (lane == 0) lds[wave] = v;
    __syncthreads();
    if (threadIdx.x == 0) {
        float s = 0.0f;
        for (int w = 0; w < 4; ++w) s += lds[w];
        lds[0] = s;
    }
    __syncthreads();
    const float r = lds[0];
    __syncthreads();
    return r;
}

__device__ __forceinline__ void haar_quad(float a, float b, float c, float d,
                                          float& cA, float& cH, float& cV, float& cD) {
    const float sab = a + b, scd = c + d, dab = a - b, dcd = c - d;
    cA = 0.5f * (sab + scd);
    cH = 0.5f * (sab - scd);
    cV = 0.5f * (dab + dcd);
    cD = 0.5f * (dab - dcd);
}

// Per-thread 8x8 version (only on the never-taken correction path in pass_b).
__device__ __forceinline__ float wavelet_block_loss(
        const float* __restrict__ blk, float t1, float t2, float t3) {
    float cA1[4][4];
    float s1 = 0.0f, s2 = 0.0f, s3 = 0.0f;
    #pragma unroll
    for (int rr = 0; rr < 4; ++rr) {
        const float4 r0a = *(const float4*)(blk + (size_t)(2 * rr) * W);
        const float4 r0b = *(const float4*)(blk + (size_t)(2 * rr) * W + 4);
        const float4 r1a = *(const float4*)(blk + (size_t)(2 * rr + 1) * W);
        const float4 r1b = *(const float4*)(blk + (size_t)(2 * rr + 1) * W + 4);
        const float top[8] = {r0a.x, r0a.y, r0a.z, r0a.w, r0b.x, r0b.y, r0b.z, r0b.w};
        const float bot[8] = {r1a.x, r1a.y, r1a.z, r1a.w, r1b.x, r1b.y, r1b.z, r1b.w};
        #pragma unroll
        for (int cc = 0; cc < 4; ++cc) {
            float cA, cH, cV, cD;
            haar_quad(top[2*cc], top[2*cc+1], bot[2*cc], bot[2*cc+1], cA, cH, cV, cD);
            s1 += fminf(fabsf(cH), t1) + fminf(fabsf(cV), t1) + fminf(fabsf(cD), t1);
            cA1[rr][cc] = cA;
        }
    }
    float cA2[2][2];
    #pragma unroll
    for (int rr = 0; rr < 2; ++rr)
        #pragma unroll
        for (int cc = 0; cc < 2; ++cc) {
            float cA, cH, cV, cD;
            haar_quad(cA1[2*rr][2*cc], cA1[2*rr][2*cc+1],
                      cA1[2*rr+1][2*cc], cA1[2*rr+1][2*cc+1], cA, cH, cV, cD);
            s2 += fminf(fabsf(cH), t2) + fminf(fabsf(cV), t2) + fminf(fabsf(cD), t2);
            cA2[rr][cc] = cA;
        }
    {
        float cA, cH, cV, cD;
        haar_quad(cA2[0][0], cA2[0][1], cA2[1][0], cA2[1][1], cA, cH, cV, cD);
        s3 = fminf(fabsf(cH), t3) + fminf(fabsf(cV), t3) + fminf(fabsf(cD), t3);
    }
    const float w1 = 1.0f / (9.0f * 65536.0f);
    const float w2 = 1.0f / (6.0f * 16384.0f);
    const float w3 = 1.0f / (3.0f * 4096.0f);
    return s1 * w1 + s2 * w2 + s3 * w3;
}

__global__ __launch_bounds__(256, 8) void pass_a(const float* __restrict__ x,
                                                 float* __restrict__ partials,
                                                 uint32_t* __restrict__ ghist,
                                                 float* __restrict__ out) {
    __shared__ uint32_t h[NBIN];
    __shared__ float lds[8];
    const int tid  = threadIdx.x;
    const int lane = tid & 63;
    const int wv   = tid >> 6;          // wave 0..3
    const int sub  = blockIdx.x;        // 0..15
    const int b    = blockIdx.y;        // 0..127

    h[tid] = 0u;
    h[tid + 256] = 0u;
    if (sub == 0 && b == 0 && tid < 2) out[tid] = 0.0f;   // init d_out
    __syncthreads();

    const float BASE = 40.0f / 400.0f;
    const float t3 = BASE * 2.0f, t2 = t3 * 0.5f, t1 = t3 * 0.25f;

    // Wave strip: 8 rows x 512 cols. Strip index R = sub*4 + wv (0..63).
    const float* strip = x + (size_t)b * W * W + (size_t)((sub * 4 + wv) * 8) * W;

    float s1 = 0.0f, s2 = 0.0f, s3 = 0.0f;

    // Two sequential 256-col halves: halves live-register pressure vs R5
    // (8 in-flight float4 + 8 cA1 instead of 16+16) so we fit 64 VGPRs.
    #pragma unroll
    for (int half = 0; half < 2; ++half) {
        const float* hb = strip + half * 256 + 4 * lane;
        float cA1[4][2];
        #pragma unroll
        for (int rp = 0; rp < 4; ++rp) {
            const float4 tp = *(const float4*)(hb + (size_t)(2 * rp) * W);
            const float4 bt = *(const float4*)(hb + (size_t)(2 * rp + 1) * W);
            float cA, cH, cV, cD;
            haar_quad(tp.x, tp.y, bt.x, bt.y, cA, cH, cV, cD);
            s1 += fminf(fabsf(cH), t1) + fminf(fabsf(cV), t1) + fminf(fabsf(cD), t1);
            cA1[rp][0] = cA;
            haar_quad(tp.z, tp.w, bt.z, bt.w, cA, cH, cV, cD);
            s1 += fminf(fabsf(cH), t1) + fminf(fabsf(cV), t1) + fminf(fabsf(cD), t1);
            cA1[rp][1] = cA;
        }
        float cA2[2];
        #pragma unroll
        for (int j = 0; j < 2; ++j) {
            float cA, cH, cV, cD;
            haar_quad(cA1[2*j][0], cA1[2*j][1], cA1[2*j+1][0], cA1[2*j+1][1],
                      cA, cH, cV, cD);
            s2 += fminf(fabsf(cH), t2) + fminf(fabsf(cV), t2) + fminf(fabsf(cD), t2);
            cA2[j] = cA;
        }
        // L3: col pair across adjacent lanes; even lanes compute + bin
        const float p0 = __shfl_xor(cA2[0], 1, 64);
        const float p1 = __shfl_xor(cA2[1], 1, 64);
        if ((lane & 1) == 0) {
            float cA, cH, cV, cD;
            haar_quad(cA2[0], p0, cA2[1], p1, cA, cH, cV, cD);
            const float aH = fabsf(cH), aV = fabsf(cV), aD = fabsf(cD);
            s3 += fminf(aH, t3) + fminf(aV, t3) + fminf(aD, t3);
            atomicAdd(&h[min((int)(aH * 256.0f), NBIN - 1)], 1u);
            atomicAdd(&h[min((int)(aV * 256.0f), NBIN - 1)], 1u);
            atomicAdd(&h[min((int)(aD * 256.0f), NBIN - 1)], 1u);
        }
    }

    // level weights: 1/3·1/3/65536 (L1), 1/2·1/3/16384 (L2), 1/1·1/3/4096 (L3)
    const float w1 = 1.0f / (9.0f * 65536.0f);
    const float w2 = 1.0f / (6.0f * 16384.0f);
    const float w3 = 1.0f / (3.0f * 4096.0f);
    const float part = s1 * w1 + s2 * w2 + s3 * w3;

    const float tot = block_reduce_sum(part, lds);   // barriers fence h[] too
    if (tid == 0) partials[b * 16 + sub] = tot;

    // plain-store this block's complete sub-histogram (no memset needed)
    uint32_t* gh = ghist + ((size_t)b * 16 + sub) * NBIN;
    gh[tid] = h[tid];
    gh[tid + 256] = h[tid + 256];
}

// One wave per batch: sum 16 sub-hists, scan for order stats 6143/6144,
// sigma from bin midpoint, finalize loss.
__global__ __launch_bounds__(64) void pass_b(const uint32_t* __restrict__ ghist,
                                             const float* __restrict__ partials,
                                             const float* __restrict__ x,
                                             float* __restrict__ out) {
    const int b = blockIdx.x;
    const int lane = threadIdx.x;   // 0..63; owns bins [8*lane, 8*lane+8)
    uint32_t c[8] = {0, 0, 0, 0, 0, 0, 0, 0};

    #pragma unroll 4
    for (int s = 0; s < 16; ++s) {
        const uint32_t* hb = ghist + ((size_t)b * 16 + s) * NBIN + lane * 8;
        const uint4 u0 = *(const uint4*)(hb);
        const uint4 u1 = *(const uint4*)(hb + 4);
        c[0] += u0.x; c[1] += u0.y; c[2] += u0.z; c[3] += u0.w;
        c[4] += u1.x; c[5] += u1.y; c[6] += u1.z; c[7] += u1.w;
    }

    uint32_t lane_sum = 0;
    #pragma unroll
    for (int j = 0; j < 8; ++j) lane_sum += c[j];

    uint32_t incl = lane_sum;
    #pragma unroll
    for (int off = 1; off < 64; off <<= 1) {
        const uint32_t v = __shfl_up(incl, off, 64);
        if (lane >= off) incl += v;
    }
    uint32_t run = incl - lane_sum;

    int bin1 = 0x7FFFFFFF, bin2 = 0x7FFFFFFF;
    #pragma unroll
    for (int j = 0; j < 8; ++j) {
        const uint32_t nxt = run + c[j];
        if (run < 6144u && nxt >= 6144u) bin1 = lane * 8 + j;
        if (run < 6145u && nxt >= 6145u) bin2 = lane * 8 + j;
        run = nxt;
    }
    #pragma unroll
    for (int off = 32; off > 0; off >>= 1) {
        bin1 = min(bin1, __shfl_down(bin1, off, 64));
        bin2 = min(bin2, __shfl_down(bin2, off, 64));
    }
    bin1 = __shfl(bin1, 0, 64);
    bin2 = __shfl(bin2, 0, 64);

    const float v1 = ((float)bin1 + 0.5f) * (1.0f / 256.0f);
    const float v2 = ((float)bin2 + 0.5f) * (1.0f / 256.0f);
    const float med = 0.5f * (v1 + v2);          // err <= 1/512 ~ 2e-3
    const float sig = med * (float)(1.0 / 0.6745);
    const float BASE = 40.0f / 400.0f;
    const float TTOP = BASE * 2.0f;
    const float t = fminf(fmaxf(sig * 2.5f, BASE * 0.5f), TTOP);

    float loss_b;
    if (t == TTOP) {
        float v = (lane < 16) ? partials[b * 16 + lane] : 0.0f;
        #pragma unroll
        for (int off = 32; off > 0; off >>= 1) v += __shfl_down(v, off, 64);
        loss_b = v;
    } else {
        // correction: recompute this batch with the true thresholds (rare)
        float part = 0.0f;
        #pragma unroll 1
        for (int k = 0; k < 64; ++k) {
            const int p = k * 64 + lane;
            const int i3 = p >> 6, j3 = p & 63;
            const float* blk = x + (size_t)b * W * W + (size_t)(i3 * 8) * W + j3 * 8;
            part += wavelet_block_loss(blk, t * 0.25f, t * 0.5f, t);
        }
        #pragma unroll
        for (int off = 32; off > 0; off >>= 1) part += __shfl_down(part, off, 64);
        loss_b = part;
    }

    if (lane == 0) {
        atomicAdd(&out[0], loss_b * (1.0f / (float)BATCH));
        atomicAdd(&out[1], sig * (1.0f / (float)BATCH));
    }
}

extern "C" void kernel_launch(void* const* d_in, const int* in_sizes, int n_in,
                              void* d_out, int out_size, void* d_ws, size_t ws_size,
                              hipStream_t stream) {
    const float* x = (const float*)d_in[0];
    float* ws = (float*)d_ws;
    float* partials = ws;                          // 2048 floats
    uint32_t* ghist = (uint32_t*)(ws + 2048);      // 128*16*512 u32 = 4 MB

    dim3 grid(16, BATCH);
    pass_a<<<grid, 256, 0, stream>>>(x, partials, ghist, (float*)d_out);
    pass_b<<<BATCH, 64, 0, stream>>>(ghist, partials, x, (float*)d_out);
}

// Round 8
// 199.123 us; speedup vs baseline: 1.2672x; 1.2171x over previous
//
#include <hip/hip_runtime.h>
#include <stdint.h>

// WaveletSparsityPrior: 3-level Haar, loss = sum_lvl w_lvl * mean min(|c|, t_lvl)
// Dispatches: memset(ghist 256KB) -> pass_a -> pass_b.
//
//  pass_a (grid 64x128, 256 thr): block stages its 16KB strip (8 rows x 512,
//    contiguous in memory) into LDS via __builtin_amdgcn_global_load_lds
//    width=16 (async, no dest VGPRs -> deep MLP, tiny register footprint;
//    R7 proved occupancy-by-coercion spills, R6/R5 showed latency-bound).
//    Haar tree from LDS: L1 in-lane -> cA1 overlay; L2 -> cA2 overlay;
//    L3 (64 thr) -> 3 global atomicAdds into per-batch 512-bin histogram.
//    Speculative t=0.2 (clip top) -> exact loss (absmax=0 through R1-R7).
//  pass_b (128 blocks x 64): scan batch histogram for order stats 6143/6144,
//    sigma from bin midpoint (err <= 2e-3 << 2e-2 threshold), t, sum 64
//    partials, 2 fp32 atomicAdds into d_out. Correction only if t != 0.2.
//
// ws layout: f32 [0,8192) partials[b*64+R]; u32 [8192, +65536) ghist[b*512+bin].

static constexpr int BATCH = 128;
static constexpr int W = 512;
static constexpr int NBIN = 512;      // bin width 1/256 over [0,2)

__device__ __forceinline__ void load16_lds(const float* g, float* s) {
    // per-lane global ptr; LDS dest = wave-uniform base + lane*16 (HW rule)
    __builtin_amdgcn_global_load_lds(
        (const __attribute__((address_space(1))) void*)g,
        (__attribute__((address_space(3))) void*)s,
        16, 0, 0);
}

__device__ __forceinline__ float block_reduce_sum(float v, float* lds) {
    #pragma unroll
    for (int off = 32; off > 0; off >>= 1)
        v += __shfl_down(v, off, 64);
    const int lane = threadIdx.x & 63;
    const int wave = threadIdx.x >> 6;
    if (lane == 0) lds[wave] = v;
    __syncthreads();
    if (threadIdx.x == 0) {
        float s = 0.0f;
        for (int w = 0; w < 4; ++w) s += lds[w];
        lds[0] = s;
    }
    __syncthreads();
    const float r = lds[0];
    __syncthreads();
    return r;
}

__device__ __forceinline__ void haar_quad(float a, float b, float c, float d,
                                          float& cA, float& cH, float& cV, float& cD) {
    const float sab = a + b, scd = c + d, dab = a - b, dcd = c - d;
    cA = 0.5f * (sab + scd);
    cH = 0.5f * (sab - scd);
    cV = 0.5f * (dab + dcd);
    cD = 0.5f * (dab - dcd);
}

// Per-thread 8x8 version (only on the never-taken correction path in pass_b).
__device__ __forceinline__ float wavelet_block_loss(
        const float* __restrict__ blk, float t1, float t2, float t3) {
    float cA1[4][4];
    float s1 = 0.0f, s2 = 0.0f, s3 = 0.0f;
    #pragma unroll
    for (int rr = 0; rr < 4; ++rr) {
        const float4 r0a = *(const float4*)(blk + (size_t)(2 * rr) * W);
        const float4 r0b = *(const float4*)(blk + (size_t)(2 * rr) * W + 4);
        const float4 r1a = *(const float4*)(blk + (size_t)(2 * rr + 1) * W);
        const float4 r1b = *(const float4*)(blk + (size_t)(2 * rr + 1) * W + 4);
        const float top[8] = {r0a.x, r0a.y, r0a.z, r0a.w, r0b.x, r0b.y, r0b.z, r0b.w};
        const float bot[8] = {r1a.x, r1a.y, r1a.z, r1a.w, r1b.x, r1b.y, r1b.z, r1b.w};
        #pragma unroll
        for (int cc = 0; cc < 4; ++cc) {
            float cA, cH, cV, cD;
            haar_quad(top[2*cc], top[2*cc+1], bot[2*cc], bot[2*cc+1], cA, cH, cV, cD);
            s1 += fminf(fabsf(cH), t1) + fminf(fabsf(cV), t1) + fminf(fabsf(cD), t1);
            cA1[rr][cc] = cA;
        }
    }
    float cA2[2][2];
    #pragma unroll
    for (int rr = 0; rr < 2; ++rr)
        #pragma unroll
        for (int cc = 0; cc < 2; ++cc) {
            float cA, cH, cV, cD;
            haar_quad(cA1[2*rr][2*cc], cA1[2*rr][2*cc+1],
                      cA1[2*rr+1][2*cc], cA1[2*rr+1][2*cc+1], cA, cH, cV, cD);
            s2 += fminf(fabsf(cH), t2) + fminf(fabsf(cV), t2) + fminf(fabsf(cD), t2);
            cA2[rr][cc] = cA;
        }
    {
        float cA, cH, cV, cD;
        haar_quad(cA2[0][0], cA2[0][1], cA2[1][0], cA2[1][1], cA, cH, cV, cD);
        s3 = fminf(fabsf(cH), t3) + fminf(fabsf(cV), t3) + fminf(fabsf(cD), t3);
    }
    const float w1 = 1.0f / (9.0f * 65536.0f);
    const float w2 = 1.0f / (6.0f * 16384.0f);
    const float w3 = 1.0f / (3.0f * 4096.0f);
    return s1 * w1 + s2 * w2 + s3 * w3;
}

__global__ __launch_bounds__(256) void pass_a(const float* __restrict__ x,
                                              float* __restrict__ partials,
                                              uint32_t* __restrict__ ghist,
                                              float* __restrict__ out) {
    __shared__ float S[8 * W];     // 16 KB staged strip; later overlaid:
                                   //   S[0..1024)    = cA1[4][256]
                                   //   S[1024..1280) = cA2[2][128]
    __shared__ float lds[8];
    const int tid  = threadIdx.x;  // 0..255
    const int lane = tid & 63;
    const int wv   = tid >> 6;     // wave 0..3
    const int R    = blockIdx.x;   // strip 0..63
    const int b    = blockIdx.y;   // batch 0..127

    if (R == 0 && b == 0 && tid < 2) out[tid] = 0.0f;   // init d_out

    // ---- async stage: strip = rows [8R, 8R+8) = 16 KB contiguous ----
    const float* strip = x + (size_t)b * W * W + (size_t)R * 8 * W;
    #pragma unroll
    for (int k = 0; k < 4; ++k) {
        const int off = wv * 1024 + k * 256;            // floats
        load16_lds(strip + off + lane * 4, &S[off]);
    }
    __syncthreads();   // drains vmcnt (compiler emits) + cross-wave visibility

    const float BASE = 40.0f / 400.0f;
    const float t3 = BASE * 2.0f, t2 = t3 * 0.5f, t1 = t3 * 0.25f;
    float s1 = 0.0f, s2 = 0.0f, s3 = 0.0f;

    // ---- L1: thread t handles quads (rp=j, cp=t), j=0..3 ----
    float c1r[4];
    #pragma unroll
    for (int j = 0; j < 4; ++j) {
        const float2 tp = *(const float2*)&S[(2 * j) * W + 2 * tid];
        const float2 bt = *(const float2*)&S[(2 * j + 1) * W + 2 * tid];
        float cA, cH, cV, cD;
        haar_quad(tp.x, tp.y, bt.x, bt.y, cA, cH, cV, cD);
        s1 += fminf(fabsf(cH), t1) + fminf(fabsf(cV), t1) + fminf(fabsf(cD), t1);
        c1r[j] = cA;
    }
    __syncthreads();   // all staged reads done -> safe to overlay cA1
    #pragma unroll
    for (int j = 0; j < 4; ++j) S[j * 256 + tid] = c1r[j];
    __syncthreads();   // cA1 ready

    // ---- L2: thread t handles quad (rp2 = t>>7, cp2 = t&127) ----
    {
        const int rp2 = tid >> 7, cp2 = tid & 127;
        const float2 tp = *(const float2*)&S[(2 * rp2) * 256 + 2 * cp2];
        const float2 bt = *(const float2*)&S[(2 * rp2 + 1) * 256 + 2 * cp2];
        float cA, cH, cV, cD;
        haar_quad(tp.x, tp.y, bt.x, bt.y, cA, cH, cV, cD);
        s2 += fminf(fabsf(cH), t2) + fminf(fabsf(cV), t2) + fminf(fabsf(cD), t2);
        S[1024 + rp2 * 128 + cp2] = cA;   // overlay region disjoint from cA1
    }
    __syncthreads();   // cA2 ready

    // ---- L3: threads 0..63, quad c3 = t; bin |details| via global atomics ----
    if (tid < 64) {
        const float2 tp = *(const float2*)&S[1024 + 0 * 128 + 2 * tid];
        const float2 bt = *(const float2*)&S[1024 + 1 * 128 + 2 * tid];
        float cA, cH, cV, cD;
        haar_quad(tp.x, tp.y, bt.x, bt.y, cA, cH, cV, cD);
        const float aH = fabsf(cH), aV = fabsf(cV), aD = fabsf(cD);
        s3 = fminf(aH, t3) + fminf(aV, t3) + fminf(aD, t3);
        uint32_t* gh = ghist + (size_t)b * NBIN;
        atomicAdd(&gh[min((int)(aH * 256.0f), NBIN - 1)], 1u);
        atomicAdd(&gh[min((int)(aV * 256.0f), NBIN - 1)], 1u);
        atomicAdd(&gh[min((int)(aD * 256.0f), NBIN - 1)], 1u);
    }

    // level weights: 1/3·1/3/65536 (L1), 1/2·1/3/16384 (L2), 1/1·1/3/4096 (L3)
    const float w1 = 1.0f / (9.0f * 65536.0f);
    const float w2 = 1.0f / (6.0f * 16384.0f);
    const float w3 = 1.0f / (3.0f * 4096.0f);
    const float tot = block_reduce_sum(s1 * w1 + s2 * w2 + s3 * w3, lds);
    if (tid == 0) partials[b * 64 + R] = tot;
}

// One wave per batch: scan 512-bin histogram for order stats 6143/6144,
// sigma from bin midpoint, finalize loss.
__global__ __launch_bounds__(64) void pass_b(const uint32_t* __restrict__ ghist,
                                             const float* __restrict__ partials,
                                             const float* __restrict__ x,
                                             float* __restrict__ out) {
    const int b = blockIdx.x;
    const int lane = threadIdx.x;   // 0..63; owns bins [8*lane, 8*lane+8)
    const uint32_t* hb = ghist + (size_t)b * NBIN + lane * 8;
    const uint4 u0 = *(const uint4*)(hb);
    const uint4 u1 = *(const uint4*)(hb + 4);
    uint32_t c[8] = {u0.x, u0.y, u0.z, u0.w, u1.x, u1.y, u1.z, u1.w};

    uint32_t lane_sum = 0;
    #pragma unroll
    for (int j = 0; j < 8; ++j) lane_sum += c[j];

    uint32_t incl = lane_sum;
    #pragma unroll
    for (int off = 1; off < 64; off <<= 1) {
        const uint32_t v = __shfl_up(incl, off, 64);
        if (lane >= off) incl += v;
    }
    uint32_t run = incl - lane_sum;

    int bin1 = 0x7FFFFFFF, bin2 = 0x7FFFFFFF;
    #pragma unroll
    for (int j = 0; j < 8; ++j) {
        const uint32_t nxt = run + c[j];
        if (run < 6144u && nxt >= 6144u) bin1 = lane * 8 + j;
        if (run < 6145u && nxt >= 6145u) bin2 = lane * 8 + j;
        run = nxt;
    }
    #pragma unroll
    for (int off = 32; off > 0; off >>= 1) {
        bin1 = min(bin1, __shfl_down(bin1, off, 64));
        bin2 = min(bin2, __shfl_down(bin2, off, 64));
    }
    bin1 = __shfl(bin1, 0, 64);
    bin2 = __shfl(bin2, 0, 64);

    const float v1 = ((float)bin1 + 0.5f) * (1.0f / 256.0f);
    const float v2 = ((float)bin2 + 0.5f) * (1.0f / 256.0f);
    const float med = 0.5f * (v1 + v2);          // err <= 1/512 ~ 2e-3
    const float sig = med * (float)(1.0 / 0.6745);
    const float BASE = 40.0f / 400.0f;
    const float TTOP = BASE * 2.0f;
    const float t = fminf(fmaxf(sig * 2.5f, BASE * 0.5f), TTOP);

    float loss_b;
    if (t == TTOP) {
        float v = partials[b * 64 + lane];       // exactly 64 partials/batch
        #pragma unroll
        for (int off = 32; off > 0; off >>= 1) v += __shfl_down(v, off, 64);
        loss_b = v;
    } else {
        // correction: recompute this batch with the true thresholds (rare)
        float part = 0.0f;
        #pragma unroll 1
        for (int k = 0; k < 64; ++k) {
            const int p = k * 64 + lane;
            const int i3 = p >> 6, j3 = p & 63;
            const float* blk = x + (size_t)b * W * W + (size_t)(i3 * 8) * W + j3 * 8;
            part += wavelet_block_loss(blk, t * 0.25f, t * 0.5f, t);
        }
        #pragma unroll
        for (int off = 32; off > 0; off >>= 1) part += __shfl_down(part, off, 64);
        loss_b = part;
    }

    if (lane == 0) {
        atomicAdd(&out[0], loss_b * (1.0f / (float)BATCH));
        atomicAdd(&out[1], sig * (1.0f / (float)BATCH));
    }
}

extern "C" void kernel_launch(void* const* d_in, const int* in_sizes, int n_in,
                              void* d_out, int out_size, void* d_ws, size_t ws_size,
                              hipStream_t stream) {
    const float* x = (const float*)d_in[0];
    float* ws = (float*)d_ws;
    float* partials = ws;                          // 8192 floats
    uint32_t* ghist = (uint32_t*)(ws + 8192);      // 128*512 u32 = 256 KB

    hipMemsetAsync(ghist, 0, (size_t)BATCH * NBIN * sizeof(uint32_t), stream);

    dim3 grid(64, BATCH);
    pass_a<<<grid, 256, 0, stream>>>(x, partials, ghist, (float*)d_out);
    pass_b<<<BATCH, 64, 0, stream>>>(ghist, partials, x, (float*)d_out);
}

// Round 9
// 193.586 us; speedup vs baseline: 1.3035x; 1.0286x over previous
//
#include <hip/hip_runtime.h>
#include <stdint.h>

// WaveletSparsityPrior: 3-level Haar, loss = sum_lvl w_lvl * mean min(|c|, t_lvl)
// Two dispatches: pass_a -> pass_b. This is the R5 configuration (measured
// 192.0 us, the session best), reinstated after R6-R8 experiments showed:
//   - coop single-dispatch (R6): occupancy-starved, 103 us kernel
//   - VGPR coercion to 32 (R7): 172 MB scratch spill, 103 us kernel
//   - async global_load_lds staging (R8): no gain (199 total)
// Cross-round invariance => pass_a sits at the device's ~3.1 TB/s read
// ceiling (134 MB / 3.1 TB/s ~ 45 us); m13 copy = 3.15 TB/s per direction
// corroborates. Remaining time is harness poison-fill/restore (~140 us).
//
//  pass_a (grid 16x128, 256 thr): each WAVE owns an 8-row x 512-col strip.
//    All global loads lane-contiguous float4 (lane i -> byte 16*i). Haar
//    L1/L2 in-lane, L3 via shfl_xor(1). 512-bin LDS histogram of |L3
//    details| plain-stored to ghist[b][sub] (no memset). Block (0,0) zeroes
//    d_out. Speculative t=0.2 (clip top) -> exact loss (absmax=0, R1-R8).
//  pass_b (128 blocks x 64): sum 16 sub-hists, median bin -> sigma
//    (bin-midpoint err <= 2e-3 << 2e-2 threshold) -> t -> finalize via
//    2 fp32 atomicAdds. Correction recompute only if t != 0.2 (never taken).
//
// ws layout: f32 [0,2048) partials[b*16+sub]; u32 [2048, +128*16*512) ghist.

static constexpr int BATCH = 128;
static constexpr int W = 512;
static constexpr int NBIN = 512;      // bin width 1/256 over [0,2)

__device__ __forceinline__ float block_reduce_sum(float v, float* lds) {
    #pragma unroll
    for (int off = 32; off > 0; off >>= 1)
        v += __shfl_down(v, off, 64);
    const int lane = threadIdx.x & 63;
    const int wave = threadIdx.x >> 6;
    if (lane == 0) lds[wave] = v;
    __syncthreads();
    if (threadIdx.x == 0) {
        float s = 0.0f;
        for (int w = 0; w < 4; ++w) s += lds[w];
        lds[0] = s;
    }
    __syncthreads();
    const float r = lds[0];
    __syncthreads();
    return r;
}

__device__ __forceinline__ void haar_quad(float a, float b, float c, float d,
                                          float& cA, float& cH, float& cV, float& cD) {
    const float sab = a + b, scd = c + d, dab = a - b, dcd = c - d;
    cA = 0.5f * (sab + scd);
    cH = 0.5f * (sab - scd);
    cV = 0.5f * (dab + dcd);
    cD = 0.5f * (dab - dcd);
}

// Per-thread 8x8 version (only on the never-taken correction path in pass_b).
__device__ __forceinline__ float wavelet_block_loss(
        const float* __restrict__ blk, float t1, float t2, float t3) {
    float cA1[4][4];
    float s1 = 0.0f, s2 = 0.0f, s3 = 0.0f;
    #pragma unroll
    for (int rr = 0; rr < 4; ++rr) {
        const float4 r0a = *(const float4*)(blk + (size_t)(2 * rr) * W);
        const float4 r0b = *(const float4*)(blk + (size_t)(2 * rr) * W + 4);
        const float4 r1a = *(const float4*)(blk + (size_t)(2 * rr + 1) * W);
        const float4 r1b = *(const float4*)(blk + (size_t)(2 * rr + 1) * W + 4);
        const float top[8] = {r0a.x, r0a.y, r0a.z, r0a.w, r0b.x, r0b.y, r0b.z, r0b.w};
        const float bot[8] = {r1a.x, r1a.y, r1a.z, r1a.w, r1b.x, r1b.y, r1b.z, r1b.w};
        #pragma unroll
        for (int cc = 0; cc < 4; ++cc) {
            float cA, cH, cV, cD;
            haar_quad(top[2*cc], top[2*cc+1], bot[2*cc], bot[2*cc+1], cA, cH, cV, cD);
            s1 += fminf(fabsf(cH), t1) + fminf(fabsf(cV), t1) + fminf(fabsf(cD), t1);
            cA1[rr][cc] = cA;
        }
    }
    float cA2[2][2];
    #pragma unroll
    for (int rr = 0; rr < 2; ++rr)
        #pragma unroll
        for (int cc = 0; cc < 2; ++cc) {
            float cA, cH, cV, cD;
            haar_quad(cA1[2*rr][2*cc], cA1[2*rr][2*cc+1],
                      cA1[2*rr+1][2*cc], cA1[2*rr+1][2*cc+1], cA, cH, cV, cD);
            s2 += fminf(fabsf(cH), t2) + fminf(fabsf(cV), t2) + fminf(fabsf(cD), t2);
            cA2[rr][cc] = cA;
        }
    {
        float cA, cH, cV, cD;
        haar_quad(cA2[0][0], cA2[0][1], cA2[1][0], cA2[1][1], cA, cH, cV, cD);
        s3 = fminf(fabsf(cH), t3) + fminf(fabsf(cV), t3) + fminf(fabsf(cD), t3);
    }
    const float w1 = 1.0f / (9.0f * 65536.0f);
    const float w2 = 1.0f / (6.0f * 16384.0f);
    const float w3 = 1.0f / (3.0f * 4096.0f);
    return s1 * w1 + s2 * w2 + s3 * w3;
}

__global__ __launch_bounds__(256) void pass_a(const float* __restrict__ x,
                                              float* __restrict__ partials,
                                              uint32_t* __restrict__ ghist,
                                              float* __restrict__ out) {
    __shared__ uint32_t h[NBIN];
    __shared__ float lds[8];
    const int tid  = threadIdx.x;
    const int lane = tid & 63;
    const int wv   = tid >> 6;          // wave 0..3
    const int sub  = blockIdx.x;        // 0..15
    const int b    = blockIdx.y;        // 0..127

    h[tid] = 0u;
    h[tid + 256] = 0u;
    if (sub == 0 && b == 0 && tid < 2) out[tid] = 0.0f;   // init d_out
    __syncthreads();

    const float BASE = 40.0f / 400.0f;
    const float t3 = BASE * 2.0f, t2 = t3 * 0.5f, t1 = t3 * 0.25f;

    // Wave strip: 8 rows x 512 cols. Strip index R = sub*4 + wv (0..63).
    const float* strip = x + (size_t)b * W * W + (size_t)((sub * 4 + wv) * 8) * W;

    float cA1A[4][2], cA1B[4][2];       // [row-pair rp][in-lane level-1 col]
    float s1 = 0.0f, s2 = 0.0f, s3 = 0.0f;

    #pragma unroll
    for (int rp = 0; rp < 4; ++rp) {
        const float* r0 = strip + (size_t)(2 * rp) * W;
        const float* r1 = strip + (size_t)(2 * rp + 1) * W;
        // perfectly lane-contiguous: lane i -> byte offset 16*i
        const float4 tA = *(const float4*)(r0 + 4 * lane);
        const float4 bA = *(const float4*)(r1 + 4 * lane);
        const float4 tB = *(const float4*)(r0 + 256 + 4 * lane);
        const float4 bB = *(const float4*)(r1 + 256 + 4 * lane);

        float cA, cH, cV, cD;
        haar_quad(tA.x, tA.y, bA.x, bA.y, cA, cH, cV, cD);
        s1 += fminf(fabsf(cH), t1) + fminf(fabsf(cV), t1) + fminf(fabsf(cD), t1);
        cA1A[rp][0] = cA;
        haar_quad(tA.z, tA.w, bA.z, bA.w, cA, cH, cV, cD);
        s1 += fminf(fabsf(cH), t1) + fminf(fabsf(cV), t1) + fminf(fabsf(cD), t1);
        cA1A[rp][1] = cA;
        haar_quad(tB.x, tB.y, bB.x, bB.y, cA, cH, cV, cD);
        s1 += fminf(fabsf(cH), t1) + fminf(fabsf(cV), t1) + fminf(fabsf(cD), t1);
        cA1B[rp][0] = cA;
        haar_quad(tB.z, tB.w, bB.z, bB.w, cA, cH, cV, cD);
        s1 += fminf(fabsf(cH), t1) + fminf(fabsf(cV), t1) + fminf(fabsf(cD), t1);
        cA1B[rp][1] = cA;
    }

    float cA2A[2], cA2B[2];             // level-2 cA, rows 0..1, in-lane col
    #pragma unroll
    for (int j = 0; j < 2; ++j) {
        float cA, cH, cV, cD;
        haar_quad(cA1A[2*j][0], cA1A[2*j][1], cA1A[2*j+1][0], cA1A[2*j+1][1],
                  cA, cH, cV, cD);
        s2 += fminf(fabsf(cH), t2) + fminf(fabsf(cV), t2) + fminf(fabsf(cD), t2);
        cA2A[j] = cA;
        haar_quad(cA1B[2*j][0], cA1B[2*j][1], cA1B[2*j+1][0], cA1B[2*j+1][1],
                  cA, cH, cV, cD);
        s2 += fminf(fabsf(cH), t2) + fminf(fabsf(cV), t2) + fminf(fabsf(cD), t2);
        cA2B[j] = cA;
    }

    // level-3: cols pair across adjacent lanes (2k, 2k+1); even lanes compute
    const float pA0 = __shfl_xor(cA2A[0], 1, 64);
    const float pA1 = __shfl_xor(cA2A[1], 1, 64);
    const float pB0 = __shfl_xor(cA2B[0], 1, 64);
    const float pB1 = __shfl_xor(cA2B[1], 1, 64);
    if ((lane & 1) == 0) {
        float cA, cH, cV, cD;
        haar_quad(cA2A[0], pA0, cA2A[1], pA1, cA, cH, cV, cD);
        float aH = fabsf(cH), aV = fabsf(cV), aD = fabsf(cD);
        s3 += fminf(aH, t3) + fminf(aV, t3) + fminf(aD, t3);
        atomicAdd(&h[min((int)(aH * 256.0f), NBIN - 1)], 1u);
        atomicAdd(&h[min((int)(aV * 256.0f), NBIN - 1)], 1u);
        atomicAdd(&h[min((int)(aD * 256.0f), NBIN - 1)], 1u);
        haar_quad(cA2B[0], pB0, cA2B[1], pB1, cA, cH, cV, cD);
        aH = fabsf(cH); aV = fabsf(cV); aD = fabsf(cD);
        s3 += fminf(aH, t3) + fminf(aV, t3) + fminf(aD, t3);
        atomicAdd(&h[min((int)(aH * 256.0f), NBIN - 1)], 1u);
        atomicAdd(&h[min((int)(aV * 256.0f), NBIN - 1)], 1u);
        atomicAdd(&h[min((int)(aD * 256.0f), NBIN - 1)], 1u);
    }

    // level weights: 1/3·1/3/65536 (L1), 1/2·1/3/16384 (L2), 1/1·1/3/4096 (L3)
    const float w1 = 1.0f / (9.0f * 65536.0f);
    const float w2 = 1.0f / (6.0f * 16384.0f);
    const float w3 = 1.0f / (3.0f * 4096.0f);
    const float part = s1 * w1 + s2 * w2 + s3 * w3;

    const float tot = block_reduce_sum(part, lds);   // barriers fence h[] too
    if (tid == 0) partials[b * 16 + sub] = tot;

    // plain-store this block's complete sub-histogram (no memset needed)
    uint32_t* gh = ghist + ((size_t)b * 16 + sub) * NBIN;
    gh[tid] = h[tid];
    gh[tid + 256] = h[tid + 256];
}

// One wave per batch: sum 16 sub-hists, scan for order stats 6143/6144,
// sigma from bin midpoint, finalize loss.
__global__ __launch_bounds__(64) void pass_b(const uint32_t* __restrict__ ghist,
                                             const float* __restrict__ partials,
                                             const float* __restrict__ x,
                                             float* __restrict__ out) {
    const int b = blockIdx.x;
    const int lane = threadIdx.x;   // 0..63; owns bins [8*lane, 8*lane+8)
    uint32_t c[8] = {0, 0, 0, 0, 0, 0, 0, 0};

    #pragma unroll 4
    for (int s = 0; s < 16; ++s) {
        const uint32_t* hb = ghist + ((size_t)b * 16 + s) * NBIN + lane * 8;
        const uint4 u0 = *(const uint4*)(hb);
        const uint4 u1 = *(const uint4*)(hb + 4);
        c[0] += u0.x; c[1] += u0.y; c[2] += u0.z; c[3] += u0.w;
        c[4] += u1.x; c[5] += u1.y; c[6] += u1.z; c[7] += u1.w;
    }

    uint32_t lane_sum = 0;
    #pragma unroll
    for (int j = 0; j < 8; ++j) lane_sum += c[j];

    uint32_t incl = lane_sum;
    #pragma unroll
    for (int off = 1; off < 64; off <<= 1) {
        const uint32_t v = __shfl_up(incl, off, 64);
        if (lane >= off) incl += v;
    }
    uint32_t run = incl - lane_sum;

    int bin1 = 0x7FFFFFFF, bin2 = 0x7FFFFFFF;
    #pragma unroll
    for (int j = 0; j < 8; ++j) {
        const uint32_t nxt = run + c[j];
        if (run < 6144u && nxt >= 6144u) bin1 = lane * 8 + j;
        if (run < 6145u && nxt >= 6145u) bin2 = lane * 8 + j;
        run = nxt;
    }
    #pragma unroll
    for (int off = 32; off > 0; off >>= 1) {
        bin1 = min(bin1, __shfl_down(bin1, off, 64));
        bin2 = min(bin2, __shfl_down(bin2, off, 64));
    }
    bin1 = __shfl(bin1, 0, 64);
    bin2 = __shfl(bin2, 0, 64);

    const float v1 = ((float)bin1 + 0.5f) * (1.0f / 256.0f);
    const float v2 = ((float)bin2 + 0.5f) * (1.0f / 256.0f);
    const float med = 0.5f * (v1 + v2);          // err <= 1/512 ~ 2e-3
    const float sig = med * (float)(1.0 / 0.6745);
    const float BASE = 40.0f / 400.0f;
    const float TTOP = BASE * 2.0f;
    const float t = fminf(fmaxf(sig * 2.5f, BASE * 0.5f), TTOP);

    float loss_b;
    if (t == TTOP) {
        float v = (lane < 16) ? partials[b * 16 + lane] : 0.0f;
        #pragma unroll
        for (int off = 32; off > 0; off >>= 1) v += __shfl_down(v, off, 64);
        loss_b = v;
    } else {
        // correction: recompute this batch with the true thresholds (rare)
        float part = 0.0f;
        #pragma unroll 1
        for (int k = 0; k < 64; ++k) {
            const int p = k * 64 + lane;
            const int i3 = p >> 6, j3 = p & 63;
            const float* blk = x + (size_t)b * W * W + (size_t)(i3 * 8) * W + j3 * 8;
            part += wavelet_block_loss(blk, t * 0.25f, t * 0.5f, t);
        }
        #pragma unroll
        for (int off = 32; off > 0; off >>= 1) part += __shfl_down(part, off, 64);
        loss_b = part;
    }

    if (lane == 0) {
        atomicAdd(&out[0], loss_b * (1.0f / (float)BATCH));
        atomicAdd(&out[1], sig * (1.0f / (float)BATCH));
    }
}

extern "C" void kernel_launch(void* const* d_in, const int* in_sizes, int n_in,
                              void* d_out, int out_size, void* d_ws, size_t ws_size,
                              hipStream_t stream) {
    const float* x = (const float*)d_in[0];
    float* ws = (float*)d_ws;
    float* partials = ws;                          // 2048 floats
    uint32_t* ghist = (uint32_t*)(ws + 2048);      // 128*16*512 u32 = 4 MB

    dim3 grid(16, BATCH);
    pass_a<<<grid, 256, 0, stream>>>(x, partials, ghist, (float*)d_out);
    pass_b<<<BATCH, 64, 0, stream>>>(ghist, partials, x, (float*)d_out);
}